// Round 9
// baseline (120.548 us; speedup 1.0000x reference)
//
#include <hip/hip_runtime.h>
#include <hip/hip_bf16.h>

typedef __bf16 bf16x8 __attribute__((ext_vector_type(8)));
typedef float  f32x4  __attribute__((ext_vector_type(4)));
typedef unsigned short u16;
typedef u16 ushort8_t __attribute__((ext_vector_type(8)));

#define PI_D 3.14159265358979323846

__device__ __forceinline__ float rfl_f(float x){
  return __builtin_bit_cast(float, __builtin_amdgcn_readfirstlane(__builtin_bit_cast(int, x)));
}
__device__ __forceinline__ u16 bf16_bits(float f){
  __bf16 b = (__bf16)f;
  return __builtin_bit_cast(u16, b);
}
__device__ __forceinline__ float bf2f(u16 u){
  return __builtin_bit_cast(float, ((unsigned)u) << 16);
}

// ---------------- K0: DCT / IDCT matrices (32x32 each, f32) ----------------
// Dm[k][i] = 2*cos(pi*k*(2i+1)/64)          (DCT, freq-major rows)
// Mm[i][k] = cos(pi*k*(2i+1)/64) * w[k]     (IDCT, space-major rows), w0=1/64 else 1/32
__global__ void k_init(float* __restrict__ Dm, float* __restrict__ Mm){
  for (int idx = threadIdx.x; idx < 1024; idx += 256){
    int r = idx >> 5, c = idx & 31;
    Dm[idx] = (float)(2.0 * cos(PI_D * (double)r * (double)(2*c+1) / 64.0));
    Mm[idx] = (float)(cos(PI_D * (double)c * (double)(2*r+1) / 64.0) * ((c==0)?0.5:1.0) / 32.0);
  }
}

// ---------------- KW2: wkb[kf][b][f][c] = sum_a dk[kf][a] * w[f][c][a*3+b]  (bf16) ----------------
__global__ __launch_bounds__(256) void k_wkb(const float* __restrict__ w,
                                             const float* __restrict__ Dm,
                                             u16* __restrict__ wkb){
  __shared__ float dks[32][3];
  int t = threadIdx.x;
  if (t < 96) dks[t/3][t%3] = Dm[(t/3)*32 + (t%3)];
  __syncthreads();
  int f = blockIdx.x, kf0 = blockIdx.y*4, c = t;
  const float* s = w + ((size_t)f*256 + c)*9;
  float wv9[9];
  #pragma unroll
  for (int j = 0; j < 9; ++j) wv9[j] = s[j];
  #pragma unroll
  for (int kq = 0; kq < 4; ++kq){
    int kf = kf0 + kq;
    float d0 = dks[kf][0], d1 = dks[kf][1], d2 = dks[kf][2];
    #pragma unroll
    for (int b = 0; b < 3; ++b){
      float v = d0*wv9[b] + d1*wv9[3+b] + d2*wv9[6+b];
      wkb[((size_t)(kf*3 + b) << 16) + (f << 8) + c] = bf16_bits(v);
    }
  }
}

// ---------------- KA2: fused DCT + transpose-write. Block = (n, 16 channels) ----------------
__global__ __launch_bounds__(256) void k_dct2(const float* __restrict__ x,
                                              const float* __restrict__ Dm,
                                              u16* __restrict__ Xt){
  __shared__ __bf16 Dmb[32][40];
  __shared__ float  xl[4][32*37];
  __shared__ __bf16 t1[4][32*40];
  __shared__ u16    st[1024][20];   // pad-20: row stride 40B = 10 dwords -> rotating banks
  int t = threadIdx.x;
  for (int idx = t; idx < 1024; idx += 256)
    Dmb[idx>>5][idx&31] = (__bf16)Dm[idx];
  __syncthreads();
  int wv = t >> 6, lane = t & 63, l4 = lane & 15, g = lane >> 4;
  bf16x8 dmf[2];
  dmf[0] = *(const bf16x8*)&Dmb[l4][g*8];
  dmf[1] = *(const bf16x8*)&Dmb[16+l4][g*8];
  int n = blockIdx.x, cb = blockIdx.y * 16;
  float* xw = xl[wv];
  __bf16* tw = t1[wv];
  f32x4 z = {0.f,0.f,0.f,0.f};
  for (int ci = 0; ci < 4; ++ci){
    int cl = wv*4 + ci;
    const float* xs = x + ((size_t)(n*256 + cb + cl)) * 1024;
    #pragma unroll
    for (int jr = 0; jr < 4; ++jr){
      int e = jr*256 + lane*4;
      float4 v = *(const float4*)(xs + e);
      float* p = xw + (e>>5)*37 + (e&31);
      p[0]=v.x; p[1]=v.y; p[2]=v.z; p[3]=v.w;
    }
    bf16x8 bf[2];
    #pragma unroll
    for (int nn = 0; nn < 2; ++nn){
      #pragma unroll
      for (int jj = 0; jj < 8; ++jj)
        bf[nn][jj] = (__bf16)xw[(g*8+jj)*37 + nn*16 + l4];
    }
    #pragma unroll
    for (int m = 0; m < 2; ++m){
      #pragma unroll
      for (int nn = 0; nn < 2; ++nn){
        f32x4 d = __builtin_amdgcn_mfma_f32_16x16x32_bf16(dmf[m], bf[nn], z, 0,0,0);
        #pragma unroll
        for (int r = 0; r < 4; ++r)
          tw[(m*16 + g*4 + r)*40 + nn*16 + l4] = (__bf16)d[r];
      }
    }
    bf16x8 a2[2];
    a2[0] = *(const bf16x8*)&tw[(l4)*40 + g*8];
    a2[1] = *(const bf16x8*)&tw[(16+l4)*40 + g*8];
    #pragma unroll
    for (int m2 = 0; m2 < 2; ++m2){
      #pragma unroll
      for (int nn2 = 0; nn2 < 2; ++nn2){
        f32x4 d = __builtin_amdgcn_mfma_f32_16x16x32_bf16(a2[m2], dmf[nn2], z, 0,0,0);
        #pragma unroll
        for (int r = 0; r < 4; ++r){
          int kk = m2*16 + g*4 + r, ll = nn2*16 + l4;
          st[kk*32 + ll][cl] = bf16_bits(d[r]);
        }
      }
    }
  }
  __syncthreads();
  #pragma unroll
  for (int rr = 0; rr < 8; ++rr){
    int kl = rr*128 + (t >> 1), half = t & 1;
    ushort4 v0 = *(const ushort4*)&st[kl][half*8];
    ushort4 v1 = *(const ushort4*)&st[kl][half*8 + 4];
    ushort8_t o;
    o[0]=v0.x; o[1]=v0.y; o[2]=v0.z; o[3]=v0.w;
    o[4]=v1.x; o[5]=v1.y; o[6]=v1.z; o[7]=v1.w;
    *(ushort8_t*)(Xt + (size_t)kl*16384 + (size_t)n*256 + cb + half*8) = o;
  }
}

// ---------------- KC: channel mix, wave-independent, barrier-free ----------------
// Block = 4 waves; wave fbw owns (kl = blockIdx.x, f-slice fbw*64..+63), computes 64n x 64f.
// B generated IN REGISTERS from wkb (K = sum_b dl[b]*wkb[kf][b][f][c]) — no LDS, no syncthreads.
// Same arithmetic expression as the cooperative version => bit-identical results.
__global__ __launch_bounds__(256) void k_mix(const u16* __restrict__ Xt,
                                             const u16* __restrict__ wkb,
                                             const float* __restrict__ Dm,
                                             u16* __restrict__ R){
  int t = threadIdx.x;
  int lane = t & 63, fbw = t >> 6;     // wave index = f-block
  int kl = blockIdx.x;
  int kf = kl >> 5, li = kl & 31;
  int l4 = lane & 15, g = lane >> 4;
  float dl0 = rfl_f(Dm[li*32 + 0]);
  float dl1 = rfl_f(Dm[li*32 + 1]);
  float dl2 = rfl_f(Dm[li*32 + 2]);
  // A: Xt[kl][mt*16+l4][cc*32 + g*8 ..+8]
  const u16* xbase = Xt + (size_t)kl*16384 + (size_t)l4*256 + g*8;
  // B source: wkb[kf][b][fbw*64 + nn*16 + l4][cc*32 + g*8 ..+8]
  const u16* wbase = wkb + ((size_t)(kf*3) << 16) + ((size_t)(fbw*64 + l4) << 8) + g*8;
  f32x4 acc[4][4];
  #pragma unroll
  for (int mt = 0; mt < 4; ++mt){
    #pragma unroll
    for (int nn = 0; nn < 4; ++nn){ f32x4 z={0.f,0.f,0.f,0.f}; acc[mt][nn]=z; }
  }
  for (int cc = 0; cc < 8; ++cc){
    bf16x8 af[4];
    #pragma unroll
    for (int mt = 0; mt < 4; ++mt)
      af[mt] = *(const bf16x8*)(xbase + mt*16*256 + cc*32);
    bf16x8 bfr[4];
    #pragma unroll
    for (int nn = 0; nn < 4; ++nn){
      const u16* wp = wbase + (nn*16 << 8) + cc*32;
      ushort8_t q0 = *(const ushort8_t*)(wp);
      ushort8_t q1 = *(const ushort8_t*)(wp + 65536);
      ushort8_t q2 = *(const ushort8_t*)(wp + 131072);
      #pragma unroll
      for (int j = 0; j < 8; ++j){
        float s = dl0*bf2f(q0[j]) + dl1*bf2f(q1[j]) + dl2*bf2f(q2[j]);
        bfr[nn][j] = (__bf16)s;
      }
    }
    #pragma unroll
    for (int mt = 0; mt < 4; ++mt){
      #pragma unroll
      for (int nn = 0; nn < 4; ++nn)
        acc[mt][nn] = __builtin_amdgcn_mfma_f32_16x16x32_bf16(af[mt], bfr[nn], acc[mt][nn], 0,0,0);
    }
  }
  // epilogue: R[kl][n][f] bf16 — f contiguous, 4x32B segments per store instr
  u16* rbase = R + ((size_t)kl*64 << 8) + fbw*64;
  #pragma unroll
  for (int mt = 0; mt < 4; ++mt){
    #pragma unroll
    for (int nn = 0; nn < 4; ++nn){
      #pragma unroll
      for (int r = 0; r < 4; ++r){
        int n = mt*16 + g*4 + r;
        rbase[(size_t)n*256 + nn*16 + l4] = bf16_bits(acc[mt][nn][r]);
      }
    }
  }
}

// ---------------- KD2: fused gather-transpose + IDCT + crop. Block = (n, 16 f) ----------------
__global__ __launch_bounds__(256) void k_idct2(const u16* __restrict__ R,
                                               const float* __restrict__ Mm,
                                               float* __restrict__ out){
  __shared__ __bf16 Mmb[32][40];
  __shared__ u16    st[1024][20];
  __shared__ __bf16 t2[4][32*40];
  int t = threadIdx.x;
  for (int idx = t; idx < 1024; idx += 256)
    Mmb[idx>>5][idx&31] = (__bf16)Mm[idx];
  int n = blockIdx.x, fbb = blockIdx.y * 16;
  #pragma unroll
  for (int rr = 0; rr < 8; ++rr){
    int kl = rr*128 + (t >> 1), half = t & 1;
    ushort8_t v = *(const ushort8_t*)(R + (size_t)kl*16384 + (size_t)n*256 + fbb + half*8);
    ushort4 a, b;
    a.x=v[0]; a.y=v[1]; a.z=v[2]; a.w=v[3];
    b.x=v[4]; b.y=v[5]; b.z=v[6]; b.w=v[7];
    *(ushort4*)&st[kl][half*8]     = a;
    *(ushort4*)&st[kl][half*8 + 4] = b;
  }
  __syncthreads();
  int wv = t>>6, lane = t&63, l4 = lane&15, g = lane>>4;
  bf16x8 mmf[2];
  mmf[0] = *(const bf16x8*)&Mmb[l4][g*8];
  mmf[1] = *(const bf16x8*)&Mmb[16+l4][g*8];
  f32x4 z = {0.f,0.f,0.f,0.f};
  __bf16* tw = t2[wv];
  for (int ci = 0; ci < 4; ++ci){
    int fl = wv*4 + ci;
    bf16x8 bfr[2];
    #pragma unroll
    for (int nn = 0; nn < 2; ++nn){
      #pragma unroll
      for (int jj = 0; jj < 8; ++jj)
        bfr[nn][jj] = __builtin_bit_cast(__bf16, st[(g*8+jj)*32 + nn*16 + l4][fl]);
    }
    #pragma unroll
    for (int m = 0; m < 2; ++m){
      #pragma unroll
      for (int nn = 0; nn < 2; ++nn){
        f32x4 d = __builtin_amdgcn_mfma_f32_16x16x32_bf16(mmf[m], bfr[nn], z, 0,0,0);
        #pragma unroll
        for (int r = 0; r < 4; ++r)
          tw[(m*16 + g*4 + r)*40 + nn*16 + l4] = (__bf16)d[r];
      }
    }
    bf16x8 a2[2];
    a2[0] = *(const bf16x8*)&tw[l4*40 + g*8];
    a2[1] = *(const bf16x8*)&tw[(16+l4)*40 + g*8];
    float* oo = out + (size_t)(n*256 + fbb + fl)*900;
    #pragma unroll
    for (int m2 = 0; m2 < 2; ++m2){
      #pragma unroll
      for (int nn2 = 0; nn2 < 2; ++nn2){
        f32x4 d = __builtin_amdgcn_mfma_f32_16x16x32_bf16(a2[m2], mmf[nn2], z, 0,0,0);
        #pragma unroll
        for (int r = 0; r < 4; ++r){
          int h = m2*16 + g*4 + r, w2 = nn2*16 + l4;
          if (h < 30 && w2 < 30) oo[h*30 + w2] = d[r];
        }
      }
    }
  }
}

// ---------------- launch ----------------
// ws layout (bytes) — peak 79,699,968:
//   Dm   @ 0          (4 KB)
//   Mm   @ 4096       (4 KB)
//   Xt   @ 8192       (33,554,432)   [kl][n][c] bf16
//   R    @ 33562624   (33,554,432)   [kl][n][f] bf16
//   wkb  @ 67117056   (12,582,912)   [kf][b][f][c] bf16
extern "C" void kernel_launch(void* const* d_in, const int* in_sizes, int n_in,
                              void* d_out, int out_size, void* d_ws, size_t ws_size,
                              hipStream_t stream){
  (void)in_sizes; (void)n_in; (void)out_size; (void)ws_size;
  const float* x  = (const float*)d_in[0];
  const float* w  = (const float*)d_in[1];
  float* out = (float*)d_out;
  char* ws = (char*)d_ws;
  float* Dm = (float*)(ws + 0);
  float* Mm = (float*)(ws + 4096);
  u16* Xt   = (u16*)(ws + 8192);
  u16* R    = (u16*)(ws + 33562624);
  u16* wkb  = (u16*)(ws + 67117056);

  hipLaunchKernelGGL(k_init,  dim3(1),        dim3(256), 0, stream, Dm, Mm);
  hipLaunchKernelGGL(k_wkb,   dim3(256,8),    dim3(256), 0, stream, w, Dm, wkb);
  hipLaunchKernelGGL(k_dct2,  dim3(64,16),    dim3(256), 0, stream, x, Dm, Xt);
  hipLaunchKernelGGL(k_mix,   dim3(1024),     dim3(256), 0, stream, Xt, wkb, Dm, R);
  hipLaunchKernelGGL(k_idct2, dim3(64,16),    dim3(256), 0, stream, R, Mm, out);
}